// Round 13
// baseline (104.595 us; speedup 1.0000x reference)
//
#include <hip/hip_runtime.h>
#include <math.h>

#define BB 4
#define NN 512
#define FIN 256
#define NH 8
#define FD 32
#define HF 256               // NH * FD
// leaky(x) = max(x, 0.21x) = CA*x + CB*|x|
#define CA 0.605f
#define CB 0.395f
#define IT 32                // i-tile rows; grid 512 = 2 blocks/CU
#define ESTR 268             // uints/e_s row: 1072B, 16B-aligned
#define GTS 260              // grT row stride in uints (16B-aligned)
#define GLX(j) ((j) ^ (((j) >> 5) & 7))
#define ALX(j) ((j) + ((j) >> 5))

typedef _Float16 h2_t __attribute__((ext_vector_type(2)));
union H2U { unsigned u; h2_t h; };
typedef __fp16 v8h __attribute__((ext_vector_type(8)));  // MFMA a/b frag
typedef float v4f __attribute__((ext_vector_type(4)));   // MFMA acc
union U8 { uint4 u4; v8h h; };

__device__ __forceinline__ h2_t pkrtz(float a, float b) {
  auto r = __builtin_amdgcn_cvt_pkrtz(a, b);
  union { decltype(r) f; h2_t h; } u;
  u.f = r;
  return u.h;
}
__device__ __forceinline__ unsigned pkrtz_u(float a, float b) {
  H2U u; u.h = pkrtz(a, b);
  return u.u;
}

// x = g2 + q2 (v_pk_add_f16); |x| (v_and 0x7fff7fff); acc += u2.|x| (v_dot2)
__device__ __forceinline__ float acc2(unsigned g, h2_t q, h2_t u, float acc) {
  H2U v; v.u = g;
  h2_t s = v.h + q;
  H2U a; a.h = s; a.u &= 0x7fff7fffu;
  return __builtin_amdgcn_fdot2(a.h, u, acc, false);
}

// 32-feature score for one j from 4 uint4 (8 fp16 each)
__device__ __forceinline__ float score16(uint4 g0, uint4 g1, uint4 g2, uint4 g3,
                                         const h2_t* qh, const h2_t* uh,
                                         float init) {
  float e0 = init, e1 = 0.f;
  e0 = acc2(g0.x, qh[0], uh[0], e0);
  e1 = acc2(g0.y, qh[1], uh[1], e1);
  e0 = acc2(g0.z, qh[2], uh[2], e0);
  e1 = acc2(g0.w, qh[3], uh[3], e1);
  e0 = acc2(g1.x, qh[4], uh[4], e0);
  e1 = acc2(g1.y, qh[5], uh[5], e1);
  e0 = acc2(g1.z, qh[6], uh[6], e0);
  e1 = acc2(g1.w, qh[7], uh[7], e1);
  e0 = acc2(g2.x, qh[8], uh[8], e0);
  e1 = acc2(g2.y, qh[9], uh[9], e1);
  e0 = acc2(g2.z, qh[10], uh[10], e0);
  e1 = acc2(g2.w, qh[11], uh[11], e1);
  e0 = acc2(g3.x, qh[12], uh[12], e0);
  e1 = acc2(g3.y, qh[13], uh[13], e1);
  e0 = acc2(g3.z, qh[14], uh[14], e0);
  e1 = acc2(g3.w, qh[15], uh[15], e1);
  return e0 + e1;
}

// ---------------------------------------------------------------------------
// Kernel 1: dual GEMM g = h @ W, both outputs fp16. (unchanged)
// ---------------------------------------------------------------------------
__global__ __launch_bounds__(256) void gemm_dual(
    const float* __restrict__ h, const float* __restrict__ Wl,
    const float* __restrict__ Wr, _Float16* __restrict__ glh,
    _Float16* __restrict__ grh) {
  const int t = threadIdx.x;
  const int row0 = blockIdx.x * 8;
  const float* __restrict__ W = blockIdx.y ? Wr : Wl;

  float acc[8] = {0.f, 0.f, 0.f, 0.f, 0.f, 0.f, 0.f, 0.f};
  const float* Wp = W + t;
  const float* hp = h + (size_t)row0 * FIN;

#pragma unroll 2
  for (int k4 = 0; k4 < FIN / 4; ++k4) {
    float4 hv[8];
#pragma unroll
    for (int r = 0; r < 8; ++r)
      hv[r] = *(const float4*)(hp + r * FIN + 4 * k4);
#pragma unroll
    for (int kk = 0; kk < 4; ++kk) {
      const float w = Wp[(size_t)(4 * k4 + kk) * HF];
#pragma unroll
      for (int r = 0; r < 8; ++r) {
        const float hval = (kk == 0) ? hv[r].x
                         : (kk == 1) ? hv[r].y
                         : (kk == 2) ? hv[r].z : hv[r].w;
        acc[r] = fmaf(hval, w, acc[r]);
      }
    }
  }

  _Float16* gp = (blockIdx.y ? grh : glh) + (size_t)row0 * HF + t;
#pragma unroll
  for (int r = 0; r < 8; ++r) gp[(size_t)r * HF] = (_Float16)acc[r];
}

// ---------------------------------------------------------------------------
// Kernel 2: fused GATv2 attention. Block = (head hh, 32-row i-tile, batch b).
// R13: 512-thread blocks -> 16 waves/CU (first true waves/CU doubling since
// R5; LDS ~78KB still fits 2 blocks/CU). Per-thread work halves everywhere:
// pre-pass 1 j, phase 1 one row x 32 j, staging 4 steps. Phase 3 = 8 waves:
// 4 output tiles x 2 K-halves, merged via part3 (stride 33). Exp-at-write
// softmax (R12, no max-pass). (512,4) pins VGPR<=128 -- watch WRITE_SIZE.
// ---------------------------------------------------------------------------
__global__ __launch_bounds__(512, 4) void gat_attn(
    const _Float16* __restrict__ glh, const _Float16* __restrict__ grh,
    const int* __restrict__ adj, const float* __restrict__ aw,
    float* __restrict__ out) {
  __shared__ __align__(16) unsigned ubuf[32 * GTS];  // 33.3 KB gl4/grT union
  __shared__ __align__(16) unsigned e_s[IT][ESTR];   // 34.3 KB fp16 p
  __shared__ float Al_s[544];                        // 2.1 KB, ALX-skewed
  __shared__ float s_part[16][33];                   // 2.1 KB row-sum parts
  __shared__ float part3[32][33];                    // 4.1 KB ph3 K-partials
  __shared__ float inv_l[IT];

  const int t = threadIdx.x;
  const int hh = blockIdx.x;
  const int i0 = blockIdx.y * IT;
  const int b = blockIdx.z;
  const int row = t & 31;  // phase-1 query row
  const int jg = t >> 5;   // 0..15, 32 j each

  uint4* gl4 = (uint4*)ubuf;  // [k4*512 + GLX(j)], k-major

  const _Float16* glp = glh + (size_t)b * NN * HF + hh * FD;

  // ---- per-thread prep: aw -> wv/uh; q row -> qh + a_r ----
  h2_t wv[16], uh[16], qh[16];
  float a_r = 0.f;
  {
#pragma unroll
    for (int f4 = 0; f4 < 8; ++f4) {
      const float4 w4 = *(const float4*)(aw + 4 * f4);
      wv[2 * f4] = pkrtz(CA * w4.x, CA * w4.y);
      wv[2 * f4 + 1] = pkrtz(CA * w4.z, CA * w4.w);
      uh[2 * f4] = pkrtz(CB * w4.x, CB * w4.y);
      uh[2 * f4 + 1] = pkrtz(CB * w4.z, CB * w4.w);
    }
    const uint4* qa =
        (const uint4*)(grh + (size_t)(b * NN + i0 + row) * HF + hh * FD);
    const uint4 q0 = qa[0], q1 = qa[1], q2 = qa[2], q3 = qa[3];
    H2U z;
    z.u = q0.x; qh[0] = z.h;  z.u = q0.y; qh[1] = z.h;
    z.u = q0.z; qh[2] = z.h;  z.u = q0.w; qh[3] = z.h;
    z.u = q1.x; qh[4] = z.h;  z.u = q1.y; qh[5] = z.h;
    z.u = q1.z; qh[6] = z.h;  z.u = q1.w; qh[7] = z.h;
    z.u = q2.x; qh[8] = z.h;  z.u = q2.y; qh[9] = z.h;
    z.u = q2.z; qh[10] = z.h; z.u = q2.w; qh[11] = z.h;
    z.u = q3.x; qh[12] = z.h; z.u = q3.y; qh[13] = z.h;
    z.u = q3.z; qh[14] = z.h; z.u = q3.w; qh[15] = z.h;
#pragma unroll
    for (int f2 = 0; f2 < 16; ++f2)
      a_r = __builtin_amdgcn_fdot2(qh[f2], wv[f2], a_r, false);
  }

  // ---- pre-pass: stage gl slice -> LDS (GLX) + Al (ALX); 1 j per thread ----
  {
    const int j = t;
    const uint4* gp = (const uint4*)(glp + (size_t)j * HF);
    const uint4 g0 = gp[0], g1 = gp[1], g2 = gp[2], g3 = gp[3];
    const int jx = GLX(j);
    gl4[0 * NN + jx] = g0;
    gl4[1 * NN + jx] = g1;
    gl4[2 * NN + jx] = g2;
    gl4[3 * NN + jx] = g3;
    float s0 = 0.f, s1 = 0.f;
    H2U v;
#define ALD(gu, i)                                                  \
  v.u = gu.x; s0 = __builtin_amdgcn_fdot2(v.h, wv[i+0], s0, false); \
  v.u = gu.y; s1 = __builtin_amdgcn_fdot2(v.h, wv[i+1], s1, false); \
  v.u = gu.z; s0 = __builtin_amdgcn_fdot2(v.h, wv[i+2], s0, false); \
  v.u = gu.w; s1 = __builtin_amdgcn_fdot2(v.h, wv[i+3], s1, false);
    ALD(g0, 0) ALD(g1, 4) ALD(g2, 8) ALD(g3, 12)
#undef ALD
    Al_s[ALX(j)] = s0 + s1;
  }
  __syncthreads();

  // ---- phase 1: p = exp(e) for 1 row x 32 j; local row sum ----
  {
    unsigned* erow = &e_s[row][jg * 16];
    const int* adjp = adj + (size_t)(i0 + row) * NN + jg * 32;
    float srow = 0.f;
#pragma unroll 2
    for (int g4 = 0; g4 < 8; ++g4) {
      const int4 m = ((const int4*)adjp)[g4];
      float p[4];
#pragma unroll
      for (int k = 0; k < 4; ++k) {
        const int j = jg * 32 + 4 * g4 + k;
        const int jx = GLX(j);
        const float e = score16(gl4[0 * NN + jx], gl4[1 * NN + jx],
                                gl4[2 * NN + jx], gl4[3 * NN + jx], qh, uh,
                                Al_s[ALX(j)] + a_r);
        const int mk = (k == 0) ? m.x : (k == 1) ? m.y : (k == 2) ? m.z : m.w;
        p[k] = mk ? __expf(e) : 0.f;
      }
      srow += (p[0] + p[1]) + (p[2] + p[3]);
      uint2 w0;
      w0.x = pkrtz_u(p[0], p[1]);
      w0.y = pkrtz_u(p[2], p[3]);
      *(uint2*)&erow[2 * g4] = w0;
    }
    s_part[jg][row] = srow;
  }
  __syncthreads();

  // ---- phase 2': stage grT (fp16 v_perm) + row-sum reduce ----
  {
    const int fq = t & 7;    // f-quad
    const int jp0 = t >> 3;  // 0..63 (j-pair)
    const unsigned* gbase =
        (const unsigned*)(grh + (size_t)b * NN * HF + hh * FD) + 2 * fq;
#pragma unroll
    for (int s2 = 0; s2 < 4; ++s2) {
      const int jp = jp0 + 64 * s2;
      const uint2 A = *(const uint2*)(gbase + (size_t)(2 * jp) * 128);
      const uint2 Bv = *(const uint2*)(gbase + (size_t)(2 * jp + 1) * 128);
      // low16 = even j (matches pkrtz packing of p in e_s)
      ubuf[(4 * fq + 0) * GTS + jp] = __builtin_amdgcn_perm(Bv.x, A.x, 0x05040100u);
      ubuf[(4 * fq + 1) * GTS + jp] = __builtin_amdgcn_perm(Bv.x, A.x, 0x07060302u);
      ubuf[(4 * fq + 2) * GTS + jp] = __builtin_amdgcn_perm(Bv.y, A.y, 0x05040100u);
      ubuf[(4 * fq + 3) * GTS + jp] = __builtin_amdgcn_perm(Bv.y, A.y, 0x07060302u);
    }
    if (t < IT) {
      float s = 0.f;
#pragma unroll
      for (int c = 0; c < 16; ++c) s += s_part[c][t];
      inv_l[t] = 1.f / s;
    }
  }
  __syncthreads();

  // ---- phase 3: MFMA C[32x32] = P . grT^T; 4 tiles x 2 K-halves = 8 waves --
  {
    const int lane = t & 63;
    const int wv3 = t >> 6;          // 0..7
    const int Mt = wv3 & 1, Nt = (wv3 >> 1) & 1, Kh = wv3 >> 2;
    const int l16 = lane & 15, q = lane >> 4;
    const unsigned* arow = &e_s[Mt * 16 + l16][0];       // A[m][k] packed p
    const unsigned* brow = &ubuf[(Nt * 16 + l16) * GTS]; // B[k][n]=grT[n][k]
    v4f acc = {0.f, 0.f, 0.f, 0.f};
#pragma unroll
    for (int s = 8 * Kh; s < 8 * Kh + 8; ++s) {
      U8 a; a.u4 = *(const uint4*)(arow + 16 * s + 4 * q);
      U8 bf; bf.u4 = *(const uint4*)(brow + 16 * s + 4 * q);
      acc = __builtin_amdgcn_mfma_f32_16x16x32_f16(a.h, bf.h, acc, 0, 0, 0);
    }
    if (Kh) {  // upper-K partials
#pragma unroll
      for (int r = 0; r < 4; ++r)
        part3[Mt * 16 + q * 4 + r][Nt * 16 + l16] = acc[r];
    }
    __syncthreads();
    if (!Kh) {  // merge, scale, store: D[row=q*4+r][col=l16]
      float* op = out + (size_t)(b * NN + i0 + Mt * 16 + q * 4) * HF +
                  hh * FD + Nt * 16 + l16;
#pragma unroll
      for (int r = 0; r < 4; ++r)
        op[(size_t)r * HF] =
            (acc[r] + part3[Mt * 16 + q * 4 + r][Nt * 16 + l16]) *
            inv_l[Mt * 16 + q * 4 + r];
    }
  }
}

// ---------------------------------------------------------------------------
extern "C" void kernel_launch(void* const* d_in, const int* in_sizes, int n_in,
                              void* d_out, int out_size, void* d_ws,
                              size_t ws_size, hipStream_t stream) {
  const float* h = (const float*)d_in[0];
  const int* adj = (const int*)d_in[1];
  const float* Wl = (const float*)d_in[2];
  const float* Wr = (const float*)d_in[3];
  const float* aw = (const float*)d_in[4];
  float* out = (float*)d_out;

  _Float16* glh = (_Float16*)d_ws;                                // 1 MB fp16
  _Float16* grh = (_Float16*)((char*)d_ws + (size_t)BB * NN * HF * 2);  // 1 MB

  dim3 gg(BB * NN / 8, 2, 1);
  gemm_dual<<<gg, 256, 0, stream>>>(h, Wl, Wr, glh, grh);

  dim3 ga(NH, NN / IT, BB);
  gat_attn<<<ga, 512, 0, stream>>>(glh, grh, adj, aw, out);
}